// Round 2
// baseline (352.351 us; speedup 1.0000x reference)
//
#include <hip/hip_runtime.h>

#define BB 4
#define SQn 2048
#define SS 2048
#define DM 256
#define DH 32

typedef unsigned short u16;
typedef unsigned int u32;
typedef _Float16 f16;
typedef __attribute__((ext_vector_type(8))) f16 f16x8;
typedef __attribute__((ext_vector_type(4))) f16 f16x4;
typedef __attribute__((ext_vector_type(4))) float f32x4;
typedef __attribute__((ext_vector_type(4))) u32 u32x4;

__device__ __forceinline__ float bf2f(u16 x){ u32 u=((u32)x)<<16; return __builtin_bit_cast(float,u); }
__device__ __forceinline__ u16 f2bf(float f){ u32 u=__builtin_bit_cast(u32,f); u32 r=(u+0x7fffu+((u>>16)&1u))>>16; return (u16)r; }

// Load 8 consecutive elements (element offset `off`) as f16, either from a
// bf16 buffer (fl=0) or an fp32 buffer (fl=1).
__device__ __forceinline__ f16x8 ld8(const void* p, size_t off, int fl)
{
    f16x8 r;
    if (fl) {
        const float* f = (const float*)p + off;
        f32x4 a = *(const f32x4*)f;
        f32x4 b = *(const f32x4*)(f + 4);
        #pragma unroll
        for (int i = 0; i < 4; ++i) { r[i] = (f16)a[i]; r[4+i] = (f16)b[i]; }
    } else {
        const u16* s = (const u16*)p + off;
        u32x4 v = *(const u32x4*)s;
        #pragma unroll
        for (int i = 0; i < 4; ++i) {
            u32 x = v[i];
            r[2*i]   = (f16)bf2f((u16)(x & 0xffff));
            r[2*i+1] = (f16)bf2f((u16)(x >> 16));
        }
    }
    return r;
}
__device__ __forceinline__ float ld1(const void* p, int idx, int fl)
{ return fl ? ((const float*)p)[idx] : bf2f(((const u16*)p)[idx]); }

// ---------------------------------------------------------------------------
// Dtype detection: bf16-packed words have a sane bf16 exponent in bits 14:7
// of the LOW half; fp32 words have uniform mantissa bits there.
// flag: 0 = bf16 inputs, 1 = fp32 inputs.
// ---------------------------------------------------------------------------
__global__ void detect_kernel(const u32* __restrict__ q, int* __restrict__ flag)
{
    int t = threadIdx.x;                 // 256
    u32 w = q[t];
    u32 e = (w >> 7) & 0xFFu;
    int vote = ((e >= 0x70u && e <= 0x85u) || ((w & 0xFFFFu) == 0u)) ? 1 : 0;
    #pragma unroll
    for (int d = 1; d < 64; d <<= 1) vote += __shfl_xor(vote, d);
    __shared__ int ps[4];
    if ((t & 63) == 0) ps[t >> 6] = vote;
    __syncthreads();
    if (t == 0) *flag = ((ps[0]+ps[1]+ps[2]+ps[3]) >= 128) ? 0 : 1;
}

// ---------------------------------------------------------------------------
// Kernel A: fused projections.  out[m,n] = sum_k X[m,k] * W[n,k] + bias[n]
//   bx <128  : q -> qf fp16 [B*SQ][256]
//   bx <256  : v -> vt fp16 [b][vd][s]  (TRANSPOSED store)
//   else     : k -> kf fp16 [S][256]
// block 256 thr (4 waves), tile 64M x 64N, f16 MFMA 16x16x32.
// ---------------------------------------------------------------------------
__global__ __launch_bounds__(256) void proj_kernel(
    const int* __restrict__ flag,
    const void* __restrict__ query, const void* __restrict__ values, const void* __restrict__ tkeys,
    const void* __restrict__ Wq, const void* __restrict__ Wqb,
    const void* __restrict__ Wk, const void* __restrict__ Wkb,
    const void* __restrict__ Wv, const void* __restrict__ Wvb,
    f16* __restrict__ qf, f16* __restrict__ kf, f16* __restrict__ vt)
{
    int fl = *flag;
    int bx = blockIdx.x;
    const void *X, *W, *Bi; int mode, rowbase;
    if (bx < 128)      { X=query;  W=Wq; Bi=Wqb; mode=0; rowbase=bx*64; }
    else if (bx < 256) { X=values; W=Wv; Bi=Wvb; mode=2; rowbase=(bx-128)*64; }
    else               { X=tkeys;  W=Wk; Bi=Wkb; mode=1; rowbase=(bx-256)*64; }
    int colbase = blockIdx.y * 64;

    __shared__ f16 Xs[64][40];   // 64 rows x 32 k, stride 80 B (16-mult)
    __shared__ f16 Ws[64][40];
    __shared__ u16 Os[64][72];   // epilogue staging (f16 bits), stride 144 B

    int t = threadIdx.x;
    int lane = t & 63, w = t >> 6;
    int quad = lane >> 4, l15 = lane & 15;

    const f32x4 fz = {0.f,0.f,0.f,0.f};
    f32x4 acc[4] = {fz,fz,fz,fz};

    for (int ks = 0; ks < 8; ++ks) {
        int k0 = ks * 32;
        {
            int row = t >> 2, ch = (t & 3) * 8;
            f16x8 xv = ld8(X, (size_t)(rowbase+row)*DM + k0 + ch, fl);
            f16x8 wv = ld8(W, (size_t)(colbase+row)*DM + k0 + ch, fl);
            *(f16x8*)(&Xs[row][ch]) = xv;
            *(f16x8*)(&Ws[row][ch]) = wv;
        }
        __syncthreads();
        f16x8 a = *(const f16x8*)(&Xs[w*16 + l15][quad*8]);
        #pragma unroll
        for (int nt = 0; nt < 4; ++nt) {
            f16x8 bfr = *(const f16x8*)(&Ws[nt*16 + l15][quad*8]);
            acc[nt] = __builtin_amdgcn_mfma_f32_16x16x32_f16(a, bfr, acc[nt], 0, 0, 0);
        }
        __syncthreads();
    }

    if (mode == 2) {
        // transposed store: element (m, n) -> vt[(b*256+n)*2048 + s]
        #pragma unroll
        for (int nt = 0; nt < 4; ++nt) {
            int col = colbase + nt*16 + l15;
            float bv = ld1(Bi, col, fl);
            int m = rowbase + w*16 + quad*4;
            int b = m >> 11, s = m & 2047;
            f16x4 pk;
            pk[0]=(f16)(acc[nt][0]+bv); pk[1]=(f16)(acc[nt][1]+bv);
            pk[2]=(f16)(acc[nt][2]+bv); pk[3]=(f16)(acc[nt][3]+bv);
            *(f16x4*)(vt + ((size_t)(b*DM + col))*SS + s) = pk;
        }
    } else {
        f16* dst = (mode == 0) ? qf : kf;
        #pragma unroll
        for (int nt = 0; nt < 4; ++nt) {
            int col = nt*16 + l15;
            float bv = ld1(Bi, colbase + col, fl);
            #pragma unroll
            for (int r = 0; r < 4; ++r)
                Os[w*16 + quad*4 + r][col] = __builtin_bit_cast(u16, (f16)(acc[nt][r] + bv));
        }
        __syncthreads();
        #pragma unroll
        for (int p = 0; p < 2; ++p) {
            int rr = (t >> 3) + p*32;
            int ch = (t & 7) * 8;
            u32x4 v = *(const u32x4*)(&Os[rr][ch]);
            *(u32x4*)(dst + (size_t)(rowbase+rr)*DM + colbase + ch) = v;
        }
    }
}

// ---------------------------------------------------------------------------
// Kernel B: rs[row] = (1/sqrt(32)) / sum_k 1/(dist[row][k] + 1e-9)
// ---------------------------------------------------------------------------
__global__ __launch_bounds__(256) void dwsum_kernel(
    const int* __restrict__ flag, const void* __restrict__ dist, float* __restrict__ rs)
{
    int fl = *flag;
    int row = blockIdx.x;
    int t = threadIdx.x;
    float s = 0.f;
    if (fl) {
        const float* p = (const float*)dist + (size_t)row * SS + t*8;
        f32x4 a = *(const f32x4*)p;
        f32x4 b = *(const f32x4*)(p + 4);
        #pragma unroll
        for (int i = 0; i < 4; ++i) { s += 1.0f/(a[i]+1e-9f); s += 1.0f/(b[i]+1e-9f); }
    } else {
        const u16* p = (const u16*)dist + (size_t)row * SS + t*8;
        u32x4 v = *(const u32x4*)p;
        #pragma unroll
        for (int i = 0; i < 4; ++i) {
            u32 x = v[i];
            s += 1.0f / (bf2f((u16)(x & 0xffff)) + 1e-9f);
            s += 1.0f / (bf2f((u16)(x >> 16))    + 1e-9f);
        }
    }
    #pragma unroll
    for (int d = 1; d < 64; d <<= 1) s += __shfl_xor(s, d);
    __shared__ float ps[4];
    if ((t & 63) == 0) ps[t >> 6] = s;
    __syncthreads();
    if (t == 0) rs[row] = 0.17677669529663687f / (ps[0] + ps[1] + ps[2] + ps[3]);
}

// ---------------------------------------------------------------------------
// Kernel C: flash attention + fused fc.  1 block = (b, 32 q-rows), 8 waves = 8 heads.
// ---------------------------------------------------------------------------
#define LDK 264
#define LDV 40
#define LDW 36
#define LDP 40
#define LDO 264

__global__ __launch_bounds__(512, 2) void attn_kernel(
    const int* __restrict__ flag,
    const void* __restrict__ dist, const float* __restrict__ rs,
    const f16* __restrict__ qf, const f16* __restrict__ kf, const f16* __restrict__ vtg,
    const void* __restrict__ fcw, const void* __restrict__ fcb,
    void* __restrict__ out)
{
    __shared__ __align__(16) char smem[62592];
    f16*   Kt  = (f16*)smem;                 // [32][264]  16896 B
    f16*   Vt  = (f16*)(smem + 16896);       // [256][40]  20480 B
    float* dwT = (float*)(smem + 37376);     // [32][36]    4608 B  (dwT[key][q])
    f16*   Ps  = (f16*)(smem + 41984);       // [8][32][40] 20480 B
    float* rsl = (float*)(smem + 62464);     // [32]

    int fl = *flag;
    int t = threadIdx.x;
    int w = t >> 6, lane = t & 63;
    int quad = lane >> 4, l15 = lane & 15;
    int b = blockIdx.y, q0 = blockIdx.x * 32;
    int h = w;

    if (t < 32) rsl[t] = rs[b*SQn + q0 + t];

    f16x8 aq[2];
    #pragma unroll
    for (int mt = 0; mt < 2; ++mt) {
        int rowg = b*SQn + q0 + mt*16 + l15;
        aq[mt] = *(const f16x8*)(qf + (size_t)rowg*DM + h*DH + quad*8);
    }

    const f32x4 fz = {0.f,0.f,0.f,0.f};
    f32x4 o[2][2] = {{fz,fz},{fz,fz}};
    float m_r[2][4], l_r[2][4];
    #pragma unroll
    for (int mt=0; mt<2; ++mt)
        #pragma unroll
        for (int r=0; r<4; ++r) { m_r[mt][r] = -1e30f; l_r[mt][r] = 0.f; }

    __syncthreads();

    for (int kt = 0; kt < 64; ++kt) {
        int kbase = kt * 32;
        // ---- stage K tile [32 keys][256 d] (from fp16 workspace) ----
        #pragma unroll
        for (int p = 0; p < 2; ++p) {
            int idx = (t + p*512) * 8;
            int row = idx >> 8, col = idx & 255;
            u32x4 v = *(const u32x4*)(kf + (size_t)(kbase+row)*DM + col);
            *(u32x4*)(Kt + row*LDK + col) = v;
        }
        // ---- stage V^T tile [256 vd][32 keys] ----
        #pragma unroll
        for (int p = 0; p < 2; ++p) {
            int idx = (t + p*512) * 8;
            int vd = idx >> 5, kc = idx & 31;
            u32x4 v = *(const u32x4*)(vtg + ((size_t)(b*DM + vd))*SS + kbase + kc);
            *(u32x4*)(Vt + vd*LDV + kc) = v;
        }
        // ---- stage dw^T tile [32 keys][32 q] (scale folded into rsl) ----
        {
            int q = t >> 4, k2 = (t & 15) * 2;
            size_t doff = ((size_t)(b*SQn + q0 + q))*SS + kbase + k2;
            float d0, d1;
            if (fl) { const float* dp = (const float*)dist + doff; d0 = dp[0]; d1 = dp[1]; }
            else {
                u32 dv = *(const u32*)((const u16*)dist + doff);
                d0 = bf2f((u16)(dv & 0xffff)); d1 = bf2f((u16)(dv >> 16));
            }
            float rr = rsl[q];
            dwT[(k2    )*LDW + q] = rr / (d0 + 1e-9f);
            dwT[(k2 + 1)*LDW + q] = rr / (d1 + 1e-9f);
        }
        __syncthreads();

        // ---- QK^T ----
        f16x8 bk[2];
        #pragma unroll
        for (int nt = 0; nt < 2; ++nt)
            bk[nt] = *(const f16x8*)(Kt + (nt*16 + l15)*LDK + h*DH + quad*8);
        f32x4 sc[2][2];
        #pragma unroll
        for (int mt = 0; mt < 2; ++mt)
            #pragma unroll
            for (int nt = 0; nt < 2; ++nt)
                sc[mt][nt] = __builtin_amdgcn_mfma_f32_16x16x32_f16(aq[mt], bk[nt], fz, 0, 0, 0);

        // ---- scores *= dw  (C elem: row = mt*16+quad*4+r, key = nt*16+l15) ----
        #pragma unroll
        for (int mt = 0; mt < 2; ++mt)
            #pragma unroll
            for (int nt = 0; nt < 2; ++nt) {
                f32x4 dw = *(const f32x4*)(dwT + (nt*16 + l15)*LDW + mt*16 + quad*4);
                sc[mt][nt] *= dw;
            }

        // ---- online softmax (row stats replicated across 16 lanes of a quad) ----
        #pragma unroll
        for (int mt = 0; mt < 2; ++mt)
            #pragma unroll
            for (int r = 0; r < 4; ++r) {
                float cm = fmaxf(sc[mt][0][r], sc[mt][1][r]);
                #pragma unroll
                for (int d = 1; d < 16; d <<= 1) cm = fmaxf(cm, __shfl_xor(cm, d));
                float mo = m_r[mt][r];
                float mn = fmaxf(mo, cm);
                float alpha = __expf(mo - mn);
                float p0 = __expf(sc[mt][0][r] - mn);
                float p1 = __expf(sc[mt][1][r] - mn);
                sc[mt][0][r] = p0; sc[mt][1][r] = p1;
                float rsum = p0 + p1;
                #pragma unroll
                for (int d = 1; d < 16; d <<= 1) rsum += __shfl_xor(rsum, d);
                l_r[mt][r] = l_r[mt][r]*alpha + rsum;
                m_r[mt][r] = mn;
                o[mt][0][r] *= alpha;
                o[mt][1][r] *= alpha;
            }

        // ---- P: C-layout -> LDS -> A-layout (per-wave slice) ----
        f16* Pw = Ps + w * 32 * LDP;
        #pragma unroll
        for (int mt = 0; mt < 2; ++mt)
            #pragma unroll
            for (int nt = 0; nt < 2; ++nt)
                #pragma unroll
                for (int r = 0; r < 4; ++r)
                    Pw[(mt*16 + quad*4 + r)*LDP + nt*16 + l15] = (f16)sc[mt][nt][r];
        __asm__ __volatile__("" ::: "memory");   // forbid compile-time reorder of the vector reads

        // ---- P @ V ----
        #pragma unroll
        for (int mt = 0; mt < 2; ++mt) {
            f16x8 ap = *(const f16x8*)(Pw + (mt*16 + l15)*LDP + quad*8);
            #pragma unroll
            for (int nt = 0; nt < 2; ++nt) {
                f16x8 bv = *(const f16x8*)(Vt + (h*DH + nt*16 + l15)*LDV + quad*8);
                o[mt][nt] = __builtin_amdgcn_mfma_f32_16x16x32_f16(ap, bv, o[mt][nt], 0, 0, 0);
            }
        }
        __syncthreads();
    }

    // ---- normalize by l ----
    #pragma unroll
    for (int mt = 0; mt < 2; ++mt)
        #pragma unroll
        for (int r = 0; r < 4; ++r) {
            float inv = 1.0f / l_r[mt][r];
            o[mt][0][r] *= inv;
            o[mt][1][r] *= inv;
        }

    __syncthreads();                       // done with Kt; reuse as o_lds
    f16* Ol = (f16*)smem;                  // [32][264]
    #pragma unroll
    for (int mt = 0; mt < 2; ++mt)
        #pragma unroll
        for (int nt = 0; nt < 2; ++nt)
            #pragma unroll
            for (int r = 0; r < 4; ++r)
                Ol[(mt*16 + quad*4 + r)*LDO + h*DH + nt*16 + l15] = (f16)o[mt][nt][r];
    __syncthreads();

    // ---- fc: out[32][256] = o @ fcw^T + fcb; wave w -> cols [w*32, w*32+32) ----
    f32x4 c[2][2] = {{fz,fz},{fz,fz}};
    for (int ks = 0; ks < 8; ++ks) {
        f16x8 a2[2];
        #pragma unroll
        for (int mt = 0; mt < 2; ++mt)
            a2[mt] = *(const f16x8*)(Ol + (mt*16 + l15)*LDO + ks*32 + quad*8);
        #pragma unroll
        for (int nt = 0; nt < 2; ++nt) {
            int n = w*32 + nt*16 + l15;
            f16x8 bw = ld8(fcw, (size_t)n*DM + ks*32 + quad*8, fl);
            #pragma unroll
            for (int mt = 0; mt < 2; ++mt)
                c[mt][nt] = __builtin_amdgcn_mfma_f32_16x16x32_f16(a2[mt], bw, c[mt][nt], 0, 0, 0);
        }
    }
    __syncthreads();                       // all Ol reads done; stage outputs as f32
    float* OutF = (float*)(smem + 16896);  // [32][264] f32 = 33792 B (dead Vt/dwT/Ps space)
    #pragma unroll
    for (int nt = 0; nt < 2; ++nt) {
        int n = w*32 + nt*16 + l15;
        float bv = ld1(fcb, n, fl);
        #pragma unroll
        for (int mt = 0; mt < 2; ++mt)
            #pragma unroll
            for (int r = 0; r < 4; ++r)
                OutF[(mt*16 + quad*4 + r)*LDO + n] = c[mt][nt][r] + bv;
    }
    __syncthreads();
    if (fl) {
        float* of = (float*)out;
        #pragma unroll
        for (int p = 0; p < 4; ++p) {
            int idx = (t + p*512) * 4;
            int row = idx >> 8, col = idx & 255;
            f32x4 v = *(const f32x4*)(OutF + row*LDO + col);
            *(f32x4*)(of + ((size_t)(b*SQn + q0 + row))*DM + col) = v;
        }
    } else {
        u16* ob = (u16*)out;
        #pragma unroll
        for (int p = 0; p < 2; ++p) {
            int idx = (t + p*512) * 8;
            int row = idx >> 8, col = idx & 255;
            f32x4 v0 = *(const f32x4*)(OutF + row*LDO + col);
            f32x4 v1 = *(const f32x4*)(OutF + row*LDO + col + 4);
            u32x4 pk;
            pk[0] = (u32)f2bf(v0[0]) | ((u32)f2bf(v0[1]) << 16);
            pk[1] = (u32)f2bf(v0[2]) | ((u32)f2bf(v0[3]) << 16);
            pk[2] = (u32)f2bf(v1[0]) | ((u32)f2bf(v1[1]) << 16);
            pk[3] = (u32)f2bf(v1[2]) | ((u32)f2bf(v1[3]) << 16);
            *(u32x4*)(ob + ((size_t)(b*SQn + q0 + row))*DM + col) = pk;
        }
    }
}

// ---------------------------------------------------------------------------
extern "C" void kernel_launch(void* const* d_in, const int* in_sizes, int n_in,
                              void* d_out, int out_size, void* d_ws, size_t ws_size,
                              hipStream_t stream)
{
    const void* query  = d_in[0];
    const void* values = d_in[1];
    const void* dist   = d_in[2];
    const void* Wq     = d_in[3];
    const void* Wqb    = d_in[4];
    const void* Wk     = d_in[5];
    const void* Wkb    = d_in[6];
    const void* Wv     = d_in[7];
    const void* Wvb    = d_in[8];
    const void* fcw    = d_in[9];
    const void* fcb    = d_in[10];
    const void* tkeys  = d_in[11];

    char* ws   = (char*)d_ws;
    f16*  qf   = (f16*)ws;                     // 4 MB  [B*SQ][256]
    f16*  kf   = (f16*)(ws + (4u << 20));      // 1 MB  [S][256]
    f16*  vt   = (f16*)(ws + (5u << 20));      // 4 MB  [b][vd][s]
    float* rsp = (float*)(ws + (9u << 20));    // 32 KB [B*SQ]
    int*  flag = (int*)(ws + (9u << 20) + 32768);

    detect_kernel<<<1, 256, 0, stream>>>((const u32*)query, flag);
    proj_kernel<<<dim3(288, 4), 256, 0, stream>>>(flag, query, values, tkeys,
                                                  Wq, Wqb, Wk, Wkb, Wv, Wvb,
                                                  qf, kf, vt);
    dwsum_kernel<<<dim3(BB * SQn), 256, 0, stream>>>(flag, dist, rsp);
    attn_kernel<<<dim3(64, 4), 512, 0, stream>>>(flag, dist, rsp, qf, kf, vt, fcw, fcb, d_out);
}

// Round 3
// 263.670 us; speedup vs baseline: 1.3363x; 1.3363x over previous
//
#include <hip/hip_runtime.h>

#define BB 4
#define SQn 2048
#define SS 2048
#define DM 256
#define DH 32

typedef unsigned short u16;
typedef unsigned int u32;
typedef _Float16 f16;
typedef __attribute__((ext_vector_type(8))) f16 f16x8;
typedef __attribute__((ext_vector_type(8))) short s16x8;
typedef __attribute__((ext_vector_type(4))) float f32x4;
typedef __attribute__((ext_vector_type(4))) u32 u32x4;
typedef __attribute__((ext_vector_type(2))) u32 u32x2;

__device__ __forceinline__ float bf2f(u16 x){ u32 u=((u32)x)<<16; return __builtin_bit_cast(float,u); }
__device__ __forceinline__ u16 f2bf(float f){ u32 u=__builtin_bit_cast(u32,f); u32 r=(u+0x7fffu+((u>>16)&1u))>>16; return (u16)r; }

// Load 8 consecutive elements as f16 from bf16 (fl=0) or fp32 (fl=1) buffer.
__device__ __forceinline__ f16x8 ld8(const void* p, size_t off, int fl)
{
    f16x8 r;
    if (fl) {
        const float* f = (const float*)p + off;
        f32x4 a = *(const f32x4*)f;
        f32x4 b = *(const f32x4*)(f + 4);
        #pragma unroll
        for (int i = 0; i < 4; ++i) { r[i] = (f16)a[i]; r[4+i] = (f16)b[i]; }
    } else {
        const u16* s = (const u16*)p + off;
        u32x4 v = *(const u32x4*)s;
        #pragma unroll
        for (int i = 0; i < 4; ++i) {
            u32 x = v[i];
            r[2*i]   = (f16)bf2f((u16)(x & 0xffff));
            r[2*i+1] = (f16)bf2f((u16)(x >> 16));
        }
    }
    return r;
}
__device__ __forceinline__ float ld1(const void* p, int idx, int fl)
{ return fl ? ((const float*)p)[idx] : bf2f(((const u16*)p)[idx]); }

// 4 consecutive f32 from bf16/fp32 buffer.
__device__ __forceinline__ f32x4 ld_d4(const void* p, int fl, size_t off)
{
    f32x4 r;
    if (fl) r = *(const f32x4*)((const float*)p + off);
    else {
        u32x2 v = *(const u32x2*)((const u16*)p + off);
        r[0]=bf2f((u16)(v[0]&0xffff)); r[1]=bf2f((u16)(v[0]>>16));
        r[2]=bf2f((u16)(v[1]&0xffff)); r[3]=bf2f((u16)(v[1]>>16));
    }
    return r;
}

// ---------------------------------------------------------------------------
// Dtype detection: 0 = bf16 inputs, 1 = fp32 inputs.
// ---------------------------------------------------------------------------
__global__ void detect_kernel(const u32* __restrict__ q, int* __restrict__ flag)
{
    int t = threadIdx.x;                 // 256
    u32 w = q[t];
    u32 e = (w >> 7) & 0xFFu;
    int vote = ((e >= 0x70u && e <= 0x85u) || ((w & 0xFFFFu) == 0u)) ? 1 : 0;
    #pragma unroll
    for (int d = 1; d < 64; d <<= 1) vote += __shfl_xor(vote, d);
    __shared__ int ps[4];
    if ((t & 63) == 0) ps[t >> 6] = vote;
    __syncthreads();
    if (t == 0) *flag = ((ps[0]+ps[1]+ps[2]+ps[3]) >= 128) ? 0 : 1;
}

// ---------------------------------------------------------------------------
// Kernel A: fused projections (f16 MFMA).  q->qf f16, k->kf f16,
// v->vt bf16 TRANSPOSED [b][d][s].
// ---------------------------------------------------------------------------
__global__ __launch_bounds__(256) void proj_kernel(
    const int* __restrict__ flag,
    const void* __restrict__ query, const void* __restrict__ values, const void* __restrict__ tkeys,
    const void* __restrict__ Wq, const void* __restrict__ Wqb,
    const void* __restrict__ Wk, const void* __restrict__ Wkb,
    const void* __restrict__ Wv, const void* __restrict__ Wvb,
    f16* __restrict__ qf, f16* __restrict__ kf, u16* __restrict__ vt)
{
    int fl = *flag;
    int bx = blockIdx.x;
    const void *X, *W, *Bi; int mode, rowbase;
    if (bx < 128)      { X=query;  W=Wq; Bi=Wqb; mode=0; rowbase=bx*64; }
    else if (bx < 256) { X=values; W=Wv; Bi=Wvb; mode=2; rowbase=(bx-128)*64; }
    else               { X=tkeys;  W=Wk; Bi=Wkb; mode=1; rowbase=(bx-256)*64; }
    int colbase = blockIdx.y * 64;

    __shared__ f16 Xs[64][40];
    __shared__ f16 Ws[64][40];
    __shared__ u16 Os[64][72];

    int t = threadIdx.x;
    int lane = t & 63, w = t >> 6;
    int quad = lane >> 4, l15 = lane & 15;

    const f32x4 fz = {0.f,0.f,0.f,0.f};
    f32x4 acc[4] = {fz,fz,fz,fz};

    for (int ks = 0; ks < 8; ++ks) {
        int k0 = ks * 32;
        {
            int row = t >> 2, ch = (t & 3) * 8;
            f16x8 xv = ld8(X, (size_t)(rowbase+row)*DM + k0 + ch, fl);
            f16x8 wv = ld8(W, (size_t)(colbase+row)*DM + k0 + ch, fl);
            *(f16x8*)(&Xs[row][ch]) = xv;
            *(f16x8*)(&Ws[row][ch]) = wv;
        }
        __syncthreads();
        f16x8 a = *(const f16x8*)(&Xs[w*16 + l15][quad*8]);
        #pragma unroll
        for (int nt = 0; nt < 4; ++nt) {
            f16x8 bfr = *(const f16x8*)(&Ws[nt*16 + l15][quad*8]);
            acc[nt] = __builtin_amdgcn_mfma_f32_16x16x32_f16(a, bfr, acc[nt], 0, 0, 0);
        }
        __syncthreads();
    }

    if (mode == 2) {
        // bf16 transposed store: (m, n) -> vt[(b*256+n)*2048 + s]
        #pragma unroll
        for (int nt = 0; nt < 4; ++nt) {
            int col = colbase + nt*16 + l15;
            float bv = ld1(Bi, col, fl);
            int m = rowbase + w*16 + quad*4;
            int b = m >> 11, s = m & 2047;
            u32x2 pk;
            pk[0] = (u32)f2bf(acc[nt][0]+bv) | ((u32)f2bf(acc[nt][1]+bv) << 16);
            pk[1] = (u32)f2bf(acc[nt][2]+bv) | ((u32)f2bf(acc[nt][3]+bv) << 16);
            *(u32x2*)(vt + ((size_t)(b*DM + col))*SS + s) = pk;
        }
    } else {
        f16* dst = (mode == 0) ? qf : kf;
        #pragma unroll
        for (int nt = 0; nt < 4; ++nt) {
            int col = nt*16 + l15;
            float bv = ld1(Bi, colbase + col, fl);
            #pragma unroll
            for (int r = 0; r < 4; ++r)
                Os[w*16 + quad*4 + r][col] = __builtin_bit_cast(u16, (f16)(acc[nt][r] + bv));
        }
        __syncthreads();
        #pragma unroll
        for (int p = 0; p < 2; ++p) {
            int rr = (t >> 3) + p*32;
            int ch = (t & 7) * 8;
            u32x4 v = *(const u32x4*)(&Os[rr][ch]);
            *(u32x4*)(dst + (size_t)(rowbase+rr)*DM + colbase + ch) = v;
        }
    }
}

// ---------------------------------------------------------------------------
// Kernel B: rs[row] = (1/sqrt(32)) / sum_k 1/(dist[row][k] + 1e-9)
// ---------------------------------------------------------------------------
__global__ __launch_bounds__(256) void dwsum_kernel(
    const int* __restrict__ flag, const void* __restrict__ dist, float* __restrict__ rs)
{
    int fl = *flag;
    int row = blockIdx.x;
    int t = threadIdx.x;
    float s = 0.f;
    if (fl) {
        const float* p = (const float*)dist + (size_t)row * SS + t*8;
        f32x4 a = *(const f32x4*)p;
        f32x4 b = *(const f32x4*)(p + 4);
        #pragma unroll
        for (int i = 0; i < 4; ++i) { s += 1.0f/(a[i]+1e-9f); s += 1.0f/(b[i]+1e-9f); }
    } else {
        const u16* p = (const u16*)dist + (size_t)row * SS + t*8;
        u32x4 v = *(const u32x4*)p;
        #pragma unroll
        for (int i = 0; i < 4; ++i) {
            u32 x = v[i];
            s += 1.0f / (bf2f((u16)(x & 0xffff)) + 1e-9f);
            s += 1.0f / (bf2f((u16)(x >> 16))    + 1e-9f);
        }
    }
    #pragma unroll
    for (int d = 1; d < 64; d <<= 1) s += __shfl_xor(s, d);
    __shared__ float ps[4];
    if ((t & 63) == 0) ps[t >> 6] = s;
    __syncthreads();
    if (t == 0) rs[row] = 0.17677669529663687f / (ps[0] + ps[1] + ps[2] + ps[3]);
}

// ---------------------------------------------------------------------------
// Kernel C: flash attention (no-max softmax, S^T orientation, zero in-loop
// barriers) + fused fc.  1 block = (b, 32 q-rows), 8 waves = 8 heads.
// ---------------------------------------------------------------------------
#define LDP 40
#define LDO 264

struct Frags { f16x8 bk[2]; s16x8 bv[2]; f32x4 dd[2][2]; };

__device__ __forceinline__ Frags load_frags(
    const f16* kf, const u16* vtg, const void* dist, int fl,
    int b, int q0, int h, int kb, int l15, int quad)
{
    Frags f;
    #pragma unroll
    for (int nt = 0; nt < 2; ++nt)
        f.bk[nt] = *(const f16x8*)(kf + (size_t)(kb + nt*16 + l15)*DM + h*DH + quad*8);
    #pragma unroll
    for (int nt = 0; nt < 2; ++nt)
        f.bv[nt] = __builtin_bit_cast(s16x8,
            *(const u32x4*)(vtg + ((size_t)(b*DM + h*DH + nt*16 + l15))*SS + kb + quad*8));
    #pragma unroll
    for (int mt = 0; mt < 2; ++mt)
        #pragma unroll
        for (int nt = 0; nt < 2; ++nt)
            f.dd[mt][nt] = ld_d4(dist, fl,
                ((size_t)(b*SQn + q0 + mt*16 + l15))*SS + kb + nt*16 + quad*4);
    return f;
}

__global__ __launch_bounds__(512) void attn_kernel(
    const int* __restrict__ flag,
    const void* __restrict__ dist, const float* __restrict__ rs,
    const f16* __restrict__ qf, const f16* __restrict__ kf, const u16* __restrict__ vtg,
    const void* __restrict__ fcw, const void* __restrict__ fcb,
    void* __restrict__ out)
{
    __shared__ __align__(16) char smem[55296];
    // loop phase: per-wave P slice [32][LDP] (bf16 bits), 2560 B each, 8 waves
    // epilogue:   Ol f16 [32][LDO] at 0 (16896 B); OutF f32 [32][LDO] at 21504

    int fl = *flag;
    int t = threadIdx.x;
    int w = t >> 6, lane = t & 63;
    int quad = lane >> 4, l15 = lane & 15;
    int b = blockIdx.y, q0 = blockIdx.x * 32;
    int h = w;

    u16* Pw = (u16*)(smem + w * 2560);

    float rsq[2];
    rsq[0] = rs[b*SQn + q0 + l15];
    rsq[1] = rs[b*SQn + q0 + 16 + l15];

    f16x8 aq[2];
    #pragma unroll
    for (int mt = 0; mt < 2; ++mt)
        aq[mt] = *(const f16x8*)(qf + (size_t)(b*SQn + q0 + mt*16 + l15)*DM + h*DH + quad*8);

    // ones-column B-fragment (bf16): B[k][0]=1, else 0 -> row-sum via MFMA
    u32 ov = (l15 == 0) ? 0x3F803F80u : 0u;
    u32x4 ovv = {ov, ov, ov, ov};
    s16x8 ones = __builtin_bit_cast(s16x8, ovv);

    const f32x4 fz = {0.f,0.f,0.f,0.f};
    f32x4 o[2][2] = {{fz,fz},{fz,fz}};
    f32x4 lacc[2] = {fz, fz};

    Frags cur = load_frags(kf, vtg, dist, fl, b, q0, h, 0, l15, quad);

    for (int kt = 0; kt < 64; ++kt) {
        int kbn = ((kt + 1) & 63) * 32;          // wrap: last prefetch reads valid (unused) memory
        Frags nxt = load_frags(kf, vtg, dist, fl, b, q0, h, kbn, l15, quad);

        // S^T = K·Q^T : C elem (key = nt*16+quad*4+r, q = mt*16+l15)
        f32x4 st[2][2];
        #pragma unroll
        for (int mt = 0; mt < 2; ++mt)
            #pragma unroll
            for (int nt = 0; nt < 2; ++nt)
                st[mt][nt] = __builtin_amdgcn_mfma_f32_16x16x32_f16(cur.bk[nt], aq[mt], fz, 0, 0, 0);

        // dw (register-resident), exp (no max: bf16 P has f32 exponent range), pack, LDS
        #pragma unroll
        for (int mt = 0; mt < 2; ++mt)
            #pragma unroll
            for (int nt = 0; nt < 2; ++nt) {
                f32x4 d = cur.dd[mt][nt];
                u32 pb[4];
                #pragma unroll
                for (int r = 0; r < 4; ++r) {
                    float dwv = rsq[mt] * __builtin_amdgcn_rcpf(d[r] + 1e-9f);
                    float p = __expf(st[mt][nt][r] * dwv);
                    pb[r] = __builtin_bit_cast(u32, p);
                }
                u32x2 pk;
                pk[0] = __builtin_amdgcn_perm(pb[1], pb[0], 0x07060302u);  // [p1.hi16|p0.hi16]
                pk[1] = __builtin_amdgcn_perm(pb[3], pb[2], 0x07060302u);
                *(u32x2*)(Pw + (mt*16 + l15)*LDP + nt*16 + quad*4) = pk;
            }
        __asm__ __volatile__("" ::: "memory");   // order the per-wave LDS transpose

        // P @ [V | 1] in bf16 (l arrives in o's C-layout; same rounded p in num & denom)
        #pragma unroll
        for (int mt = 0; mt < 2; ++mt) {
            s16x8 ap = *(const s16x8*)(Pw + (mt*16 + l15)*LDP + quad*8);
            lacc[mt] = __builtin_amdgcn_mfma_f32_16x16x32_bf16(ap, ones, lacc[mt], 0, 0, 0);
            #pragma unroll
            for (int nt = 0; nt < 2; ++nt)
                o[mt][nt] = __builtin_amdgcn_mfma_f32_16x16x32_bf16(ap, cur.bv[nt], o[mt][nt], 0, 0, 0);
        }
        cur = nxt;
    }

    // ---- normalize: l for row (mt,quad,r) lives at lane (l15=0, quad), col 0 ----
    #pragma unroll
    for (int mt = 0; mt < 2; ++mt)
        #pragma unroll
        for (int r = 0; r < 4; ++r) {
            float lv = __shfl(lacc[mt][r], lane & 48);
            float inv = 1.0f / lv;
            o[mt][0][r] *= inv;
            o[mt][1][r] *= inv;
        }

    // ---- epilogue: fused fc (as validated in R2) ----
    __syncthreads();                       // all waves done with P slices
    f16* Ol = (f16*)smem;                  // [32][LDO]
    #pragma unroll
    for (int mt = 0; mt < 2; ++mt)
        #pragma unroll
        for (int nt = 0; nt < 2; ++nt)
            #pragma unroll
            for (int r = 0; r < 4; ++r)
                Ol[(mt*16 + quad*4 + r)*LDO + h*DH + nt*16 + l15] = (f16)o[mt][nt][r];
    __syncthreads();

    f32x4 c[2][2] = {{fz,fz},{fz,fz}};
    for (int ks = 0; ks < 8; ++ks) {
        f16x8 a2[2];
        #pragma unroll
        for (int mt = 0; mt < 2; ++mt)
            a2[mt] = *(const f16x8*)(Ol + (mt*16 + l15)*LDO + ks*32 + quad*8);
        #pragma unroll
        for (int nt = 0; nt < 2; ++nt) {
            int n = w*32 + nt*16 + l15;
            f16x8 bw = ld8(fcw, (size_t)n*DM + ks*32 + quad*8, fl);
            #pragma unroll
            for (int mt = 0; mt < 2; ++mt)
                c[mt][nt] = __builtin_amdgcn_mfma_f32_16x16x32_f16(a2[mt], bw, c[mt][nt], 0, 0, 0);
        }
    }
    float* OutF = (float*)(smem + 21504);  // [32][LDO] f32, disjoint from Ol
    #pragma unroll
    for (int nt = 0; nt < 2; ++nt) {
        int n = w*32 + nt*16 + l15;
        float bv = ld1(fcb, n, fl);
        #pragma unroll
        for (int mt = 0; mt < 2; ++mt)
            #pragma unroll
            for (int r = 0; r < 4; ++r)
                OutF[(mt*16 + quad*4 + r)*LDO + n] = c[mt][nt][r] + bv;
    }
    __syncthreads();
    if (fl) {
        float* of = (float*)out;
        #pragma unroll
        for (int p = 0; p < 4; ++p) {
            int idx = (t + p*512) * 4;
            int row = idx >> 8, col = idx & 255;
            f32x4 v = *(const f32x4*)(OutF + row*LDO + col);
            *(f32x4*)(of + ((size_t)(b*SQn + q0 + row))*DM + col) = v;
        }
    } else {
        u16* ob = (u16*)out;
        #pragma unroll
        for (int p = 0; p < 2; ++p) {
            int idx = (t + p*512) * 8;
            int row = idx >> 8, col = idx & 255;
            f32x4 v0 = *(const f32x4*)(OutF + row*LDO + col);
            f32x4 v1 = *(const f32x4*)(OutF + row*LDO + col + 4);
            u32x4 pk;
            pk[0] = (u32)f2bf(v0[0]) | ((u32)f2bf(v0[1]) << 16);
            pk[1] = (u32)f2bf(v0[2]) | ((u32)f2bf(v0[3]) << 16);
            pk[2] = (u32)f2bf(v1[0]) | ((u32)f2bf(v1[1]) << 16);
            pk[3] = (u32)f2bf(v1[2]) | ((u32)f2bf(v1[3]) << 16);
            *(u32x4*)(ob + ((size_t)(b*SQn + q0 + row))*DM + col) = pk;
        }
    }
}

// ---------------------------------------------------------------------------
extern "C" void kernel_launch(void* const* d_in, const int* in_sizes, int n_in,
                              void* d_out, int out_size, void* d_ws, size_t ws_size,
                              hipStream_t stream)
{
    const void* query  = d_in[0];
    const void* values = d_in[1];
    const void* dist   = d_in[2];
    const void* Wq     = d_in[3];
    const void* Wqb    = d_in[4];
    const void* Wk     = d_in[5];
    const void* Wkb    = d_in[6];
    const void* Wv     = d_in[7];
    const void* Wvb    = d_in[8];
    const void* fcw    = d_in[9];
    const void* fcb    = d_in[10];
    const void* tkeys  = d_in[11];

    char* ws   = (char*)d_ws;
    f16*  qf   = (f16*)ws;                     // 4 MB  [B*SQ][256] f16
    f16*  kf   = (f16*)(ws + (4u << 20));      // 1 MB  [S][256] f16
    u16*  vt   = (u16*)(ws + (5u << 20));      // 4 MB  [b][d][s] bf16
    float* rsp = (float*)(ws + (9u << 20));    // 32 KB [B*SQ]
    int*  flag = (int*)(ws + (9u << 20) + 32768);

    detect_kernel<<<1, 256, 0, stream>>>((const u32*)query, flag);
    proj_kernel<<<dim3(288, 4), 256, 0, stream>>>(flag, query, values, tkeys,
                                                  Wq, Wqb, Wk, Wkb, Wv, Wvb,
                                                  qf, kf, vt);
    dwsum_kernel<<<dim3(BB * SQn), 256, 0, stream>>>(flag, dist, rsp);
    attn_kernel<<<dim3(64, 4), 512, 0, stream>>>(flag, dist, rsp, qf, kf, vt, fcw, fcb, d_out);
}